// Round 8
// baseline (1748.341 us; speedup 1.0000x reference)
//
#include <hip/hip_runtime.h>
#include <math.h>

#define HH  64
#define TT  2048
#define IND 7
#define NT  1024

typedef float f4 __attribute__((ext_vector_type(4)));
typedef unsigned int u2v __attribute__((ext_vector_type(2)));

__device__ __forceinline__ f4 fma4(f4 a, f4 b, f4 c) {
    return __builtin_elementwise_fma(a, b, c);
}

// sum with lane^32 partner on the VALU pipe (v_permlane32_swap, gfx950)
__device__ __forceinline__ float sum_x32(float x) {
#if __has_builtin(__builtin_amdgcn_permlane32_swap)
    u2v r = __builtin_amdgcn_permlane32_swap(__float_as_uint(x), __float_as_uint(x), false, false);
    return __uint_as_float(r.x) + __uint_as_float(r.y);
#else
    return x + __shfl_xor(x, 32);
#endif
}

template <int CTRL>
__device__ __forceinline__ float qperm(float x) {
    return __int_as_float(__builtin_amdgcn_update_dpp(0, __float_as_int(x), CTRL, 0xf, 0xf, true));
}
#define QP_X1 0xB1  // quad_perm(1,0,3,2)
#define QP_X2 0x4E  // quad_perm(2,3,0,1)
#define QP_X3 0x1B  // quad_perm(3,2,1,0)

// gate activation; tanh sector's pre-activation is pre-scaled by 2 via weights
__device__ __forceinline__ float gact(float a, bool is_t) {
    float e  = __expf(-a);
    float sg = __fdividef(1.0f, 1.0f + e);
    return is_t ? fmaf(2.0f, sg, -1.0f) : sg;
}
__device__ __forceinline__ float tanh_s(float c) {
    float e = __expf(-2.0f * c);
    return fmaf(2.0f, __fdividef(1.0f, 1.0f + e), -1.0f);
}

__global__ __launch_bounds__(NT) __attribute__((amdgpu_waves_per_eu(4, 4)))
void lstm2_fused(
    const float* __restrict__ x,     // (B,7,2048)
    const float* __restrict__ Wih0,  // (256,7)
    const float* __restrict__ Whh0,  // (256,64)
    const float* __restrict__ bih0, const float* __restrict__ bhh0,
    const float* __restrict__ Wih1,  // (256,64)
    const float* __restrict__ Whh1,  // (256,64)
    const float* __restrict__ bih1, const float* __restrict__ bhh1,
    const float* __restrict__ W1,    // (10,64)
    const float* __restrict__ b1v,   // (10)
    const float* __restrict__ gmma, const float* __restrict__ beta,
    const float* __restrict__ rm,   const float* __restrict__ rv,
    const float* __restrict__ W2,   // (1,10)
    const float* __restrict__ b2,   // (1)
    float* __restrict__ out)         // (B,1)
{
    const int b    = blockIdx.x;
    const int tid  = threadIdx.x;
    const int grp  = tid >> 9;            // 0: L0 waves 0-7, 1: L1 waves 8-15
    const int lane = tid & 63;
    const int wv   = (tid >> 6) & 7;      // wave index within group (j high bits)
    const int s    = lane & 3;            // gate 0:i 1:f 2:g 3:o (quad-local)
    const int kh   = lane >> 5;           // k-half (lane bit 5 -> permlane32 reduce)
    const int j    = (wv << 3) | ((lane >> 2) & 7);   // hidden unit 0..63
    const int g    = (s << 6) | j;        // gate row 0..255

    __shared__ __align__(16) float xT[TT][8];     // 64 KB, xT[t][0..6], [7]=0 pad
    __shared__ __align__(16) float h0s[2][HH];
    __shared__ __align__(16) float h1s[2][HH];
    __shared__ float yv[10];

    // ---- stage x[b] transposed ----
    {
        const float* xg = x + (size_t)b * (IND * TT);
        for (int i = tid; i < IND * TT; i += NT) {
            int d = i >> 11;
            int t = i & (TT - 1);
            xT[t][d] = xg[i];
        }
        for (int t = tid; t < TT; t += NT) xT[t][7] = 0.0f;
        if (tid < HH) { h0s[1][tid] = 0.0f; h1s[0][tid] = 0.0f; h1s[1][tid] = 0.0f; }
    }

    const float sc   = (s == 2) ? 2.0f : 1.0f;   // exact pow2 pre-scale for tanh gate
    const bool  is_t = (s == 2);
    const bool  a1b  = (s & 1) != 0;
    const bool  a2b  = (s & 2) != 0;
    const bool  pubL = ((lane & 35) == 0);       // s==0 && kh==0

    __syncthreads();

    if (grp == 0) {
        // ============ LAYER-0 GROUP: computes h0(tick) at tick ============
        f4 w[8];
        {
            const f4* pw = (const f4*)(Whh0 + g * HH + 32 * kh);
            #pragma unroll
            for (int r = 0; r < 8; ++r) w[r] = pw[r] * sc;
        }
        f4 xw;
        if (kh == 0) { xw.x = Wih0[g*IND+0]; xw.y = Wih0[g*IND+1]; xw.z = Wih0[g*IND+2]; xw.w = Wih0[g*IND+3]; }
        else         { xw.x = Wih0[g*IND+4]; xw.y = Wih0[g*IND+5]; xw.z = Wih0[g*IND+6]; xw.w = 0.0f; }
        xw *= sc;
        const float bg = (kh == 0) ? (bih0[g] + bhh0[g]) * sc : 0.0f;

        float c0 = 0.0f;
        f4 xq = *((const f4*)&xT[0][4 * kh]);

        for (int tick = 0; tick <= TT; ++tick) {
            const int p = tick & 1;
            if (tick < TT) {
                const f4* hp = (const f4*)&h0s[p ^ 1][32 * kh];   // broadcast
                f4 A0; A0.x = bg; A0.y = 0.f; A0.z = 0.f; A0.w = 0.f;
                A0 = fma4(xw, xq, A0);
                f4 A1 = (f4)(0.0f);
                #pragma unroll
                for (int r = 0; r < 8; r += 2) {
                    A0 = fma4(w[r],     hp[r],     A0);
                    A1 = fma4(w[r + 1], hp[r + 1], A1);
                }
                f4 am = A0 + A1;
                float a = sum_x32((am.x + am.y) + (am.z + am.w));
                float act = gact(a, is_t);
                // quad gather: gate t of this unit sits at lane s^t
                float x1 = qperm<QP_X1>(act);
                float x2 = qperm<QP_X2>(act);
                float x3 = qperm<QP_X3>(act);
                float p02 = act * x2, p13 = x1 * x3;
                float ig = a1b ? p13 : p02;                 // i*g
                float t1 = a2b ? x2 : act, t2 = a2b ? x3 : x1;
                float fv = a1b ? t1 : t2;                   // f
                float o1 = a2b ? act : x2, o2 = a2b ? x1 : x3;
                float ov = a1b ? o1 : o2;                   // o
                c0 = fmaf(fv, c0, ig);
                float hn = ov * tanh_s(c0);
                if (pubL) h0s[p][j] = hn;
                const int tn = (tick + 1) & (TT - 1);
                xq = *((const f4*)&xT[tn][4 * kh]);
            }
            __syncthreads();
        }
    } else {
        // ====== LAYER-1 GROUP: computes h1(tick-1) at tick (one behind) ======
        f4 wi[8], wh[8];
        {
            const f4* pa = (const f4*)(Wih1 + g * HH + 32 * kh);
            const f4* pb = (const f4*)(Whh1 + g * HH + 32 * kh);
            #pragma unroll
            for (int r = 0; r < 8; ++r) { wi[r] = pa[r] * sc; wh[r] = pb[r] * sc; }
        }
        const float bg = (kh == 0) ? (bih1[g] + bhh1[g]) * sc : 0.0f;

        float c1 = 0.0f;

        for (int tick = 0; tick <= TT; ++tick) {
            const int p = tick & 1;
            if (tick > 0) {
                const f4* hp0 = (const f4*)&h0s[p ^ 1][32 * kh];  // h0(tick-1)
                const f4* hp1 = (const f4*)&h1s[p ^ 1][32 * kh];  // h1(tick-2)
                f4 A0; A0.x = bg; A0.y = 0.f; A0.z = 0.f; A0.w = 0.f;
                f4 A1 = (f4)(0.0f), A2 = (f4)(0.0f), A3 = (f4)(0.0f);
                #pragma unroll
                for (int r = 0; r < 8; r += 2) {
                    A0 = fma4(wi[r],     hp0[r],     A0);
                    A1 = fma4(wi[r + 1], hp0[r + 1], A1);
                    A2 = fma4(wh[r],     hp1[r],     A2);
                    A3 = fma4(wh[r + 1], hp1[r + 1], A3);
                }
                f4 am = (A0 + A1) + (A2 + A3);
                float a = sum_x32((am.x + am.y) + (am.z + am.w));
                float act = gact(a, is_t);
                float x1 = qperm<QP_X1>(act);
                float x2 = qperm<QP_X2>(act);
                float x3 = qperm<QP_X3>(act);
                float p02 = act * x2, p13 = x1 * x3;
                float ig = a1b ? p13 : p02;
                float t1 = a2b ? x2 : act, t2 = a2b ? x3 : x1;
                float fv = a1b ? t1 : t2;
                float o1 = a2b ? act : x2, o2 = a2b ? x1 : x3;
                float ov = a1b ? o1 : o2;
                c1 = fmaf(fv, c1, ig);
                float hn = ov * tanh_s(c1);
                if (pubL) h1s[p][j] = hn;
            }
            __syncthreads();
        }
    }

    // h1(TT-1) was stored at tick TT into h1s[TT&1] = h1s[0]
    if (tid < 10) {
        float y = b1v[tid];
        #pragma unroll
        for (int k = 0; k < HH; ++k) y += W1[tid * HH + k] * h1s[0][k];
        y = (y - rm[tid]) * rsqrtf(rv[tid] + 1e-5f) * gmma[tid] + beta[tid];
        y = fmaxf(y, 0.0f);
        yv[tid] = y * W2[tid];
    }
    __syncthreads();
    if (tid == 0) {
        float sacc = b2[0];
        #pragma unroll
        for (int k = 0; k < 10; ++k) sacc += yv[k];
        out[b] = sacc;
    }
}

extern "C" void kernel_launch(void* const* d_in, const int* in_sizes, int n_in,
                              void* d_out, int out_size, void* d_ws, size_t ws_size,
                              hipStream_t stream) {
    const float* x    = (const float*)d_in[0];
    const float* Wih0 = (const float*)d_in[1];
    const float* Whh0 = (const float*)d_in[2];
    const float* bih0 = (const float*)d_in[3];
    const float* bhh0 = (const float*)d_in[4];
    const float* Wih1 = (const float*)d_in[5];
    const float* Whh1 = (const float*)d_in[6];
    const float* bih1 = (const float*)d_in[7];
    const float* bhh1 = (const float*)d_in[8];
    const float* W1   = (const float*)d_in[9];
    const float* b1   = (const float*)d_in[10];
    const float* gmma = (const float*)d_in[11];
    const float* beta = (const float*)d_in[12];
    const float* rm   = (const float*)d_in[13];
    const float* rv   = (const float*)d_in[14];
    const float* W2   = (const float*)d_in[15];
    const float* b2   = (const float*)d_in[16];

    const int B = in_sizes[0] / (IND * TT);   // 256

    lstm2_fused<<<dim3(B), dim3(NT), 0, stream>>>(
        x, Wih0, Whh0, bih0, bhh0, Wih1, Whh1, bih1, bhh1,
        W1, b1, gmma, beta, rm, rv, W2, b2, (float*)d_out);
}

// Round 9
// 1406.699 us; speedup vs baseline: 1.2429x; 1.2429x over previous
//
#include <hip/hip_runtime.h>
#include <math.h>

#define HH  64
#define TT  2048
#define IND 7
#define NT  512

typedef float f2 __attribute__((ext_vector_type(2)));
typedef unsigned int u2v __attribute__((ext_vector_type(2)));

// forced packed fp32 FMA on native f2 (VGPR pair): acc += a*b, one instr
__device__ __forceinline__ void pk(f2& acc, f2 a, f2 b) {
    asm("v_pk_fma_f32 %0, %1, %2, %0" : "+v"(acc) : "v"(a), "v"(b));
}

// value held by the lane^32 partner (VALU pipe, v_permlane32_swap)
__device__ __forceinline__ float partner32(float x, int kh) {
#if __has_builtin(__builtin_amdgcn_permlane32_swap)
    u2v r = __builtin_amdgcn_permlane32_swap(__float_as_uint(x), __float_as_uint(x), false, false);
    // r.x = low-half value, r.y = high-half value (per-lane replicated)
    return kh ? __uint_as_float(r.x) : __uint_as_float(r.y);
#else
    return __shfl_xor(x, 32);
#endif
}

template <int CTRL>
__device__ __forceinline__ float qperm(float x) {
    return __int_as_float(__builtin_amdgcn_update_dpp(0, __float_as_int(x), CTRL, 0xf, 0xf, true));
}
#define QP_X1 0xB1  // quad_perm(1,0,3,2)
#define QP_X2 0x4E  // quad_perm(2,3,0,1)
#define QP_X3 0x1B  // quad_perm(3,2,1,0)

__device__ __forceinline__ float gact(float a, bool is_t) {
    float e  = __expf(-a);
    float sg = __fdividef(1.0f, 1.0f + e);
    return is_t ? fmaf(2.0f, sg, -1.0f) : sg;
}
__device__ __forceinline__ float tanh_s(float c) {
    float e = __expf(-2.0f * c);
    return fmaf(2.0f, __fdividef(1.0f, 1.0f + e), -1.0f);
}

__global__ __launch_bounds__(NT) __attribute__((amdgpu_waves_per_eu(2, 2)))
void lstm2_fused(
    const float* __restrict__ x,     // (B,7,2048)
    const float* __restrict__ Wih0,  // (256,7)
    const float* __restrict__ Whh0,  // (256,64)
    const float* __restrict__ bih0, const float* __restrict__ bhh0,
    const float* __restrict__ Wih1,  // (256,64)
    const float* __restrict__ Whh1,  // (256,64)
    const float* __restrict__ bih1, const float* __restrict__ bhh1,
    const float* __restrict__ W1,    // (10,64)
    const float* __restrict__ b1v,   // (10)
    const float* __restrict__ gmma, const float* __restrict__ beta,
    const float* __restrict__ rm,   const float* __restrict__ rv,
    const float* __restrict__ W2,   // (1,10)
    const float* __restrict__ b2,   // (1)
    float* __restrict__ out)         // (B,1)
{
    const int b    = blockIdx.x;
    const int tid  = threadIdx.x;
    const int grp  = tid >> 8;           // 0: L0 waves 0-3, 1: L1 waves 4-7
    const int lane = tid & 63;
    const int wv   = (tid >> 6) & 3;     // wave in group
    const int s    = lane & 3;           // gate 0:i 1:f 2:g 3:o (quad-local)
    const int q    = (lane >> 2) & 7;
    const int kh   = lane >> 5;          // k-half (lane bit 5)
    const int jA   = (wv << 3) | q;      // unit A: 0..31
    const int gA   = (s << 6) | jA;      // gate row of unit A
    const int gB   = gA + 32;            // gate row of unit B (jA+32)
    const int jown = jA + (kh << 5);     // unit this lane finishes

    __shared__ __align__(16) float xT[TT][8];     // 64 KB, xT[t][0..6], [7]=0
    __shared__ __align__(16) float h0s[2][HH];
    __shared__ __align__(16) float h1s[2][HH];
    __shared__ float yv[10];

    // ---- stage x[b] transposed ----
    {
        const float* xg = x + (size_t)b * (IND * TT);
        for (int i = tid; i < IND * TT; i += NT) {
            int d = i >> 11;
            int t = i & (TT - 1);
            xT[t][d] = xg[i];
        }
        for (int t = tid; t < TT; t += NT) xT[t][7] = 0.0f;
        if (tid < HH) { h0s[1][tid] = 0.0f; h1s[0][tid] = 0.0f; h1s[1][tid] = 0.0f; }
    }

    const float sc   = (s == 2) ? 2.0f : 1.0f;   // exact pre-scale for tanh gate
    const bool  is_t = (s == 2);
    const bool  a1b  = (s & 1) != 0;
    const bool  a2b  = (s & 2) != 0;
    const bool  pubL = (s == 0);                 // one publisher per unit

    __syncthreads();

    if (grp == 0) {
        // ============ LAYER-0 GROUP: computes h0(tick) at tick ============
        f2 whA[16], whB[16];
        {
            const f2* pA = (const f2*)(Whh0 + gA * HH + 32 * kh);
            const f2* pB = (const f2*)(Whh0 + gB * HH + 32 * kh);
            #pragma unroll
            for (int r = 0; r < 16; ++r) { whA[r] = pA[r] * sc; whB[r] = pB[r] * sc; }
        }
        f2 xwA0, xwA1, xwB0, xwB1;
        if (kh == 0) {
            xwA0 = f2{Wih0[gA*IND+0], Wih0[gA*IND+1]}; xwA1 = f2{Wih0[gA*IND+2], Wih0[gA*IND+3]};
            xwB0 = f2{Wih0[gB*IND+0], Wih0[gB*IND+1]}; xwB1 = f2{Wih0[gB*IND+2], Wih0[gB*IND+3]};
        } else {
            xwA0 = f2{Wih0[gA*IND+4], Wih0[gA*IND+5]}; xwA1 = f2{Wih0[gA*IND+6], 0.0f};
            xwB0 = f2{Wih0[gB*IND+4], Wih0[gB*IND+5]}; xwB1 = f2{Wih0[gB*IND+6], 0.0f};
        }
        xwA0 *= sc; xwA1 *= sc; xwB0 *= sc; xwB1 *= sc;
        const float bgA = (kh == 0) ? (bih0[gA] + bhh0[gA]) * sc : 0.0f;
        const float bgB = (kh == 0) ? (bih0[gB] + bhh0[gB]) * sc : 0.0f;

        float c0 = 0.0f;                 // cell of unit jown
        f2 xa = *((const f2*)&xT[0][4 * kh]);
        f2 xb = *((const f2*)&xT[0][4 * kh + 2]);

        for (int tick = 0; tick <= TT; ++tick) {
            const int p = tick & 1;
            if (tick < TT) {
                const f2* hp = (const f2*)&h0s[p ^ 1][32 * kh];
                f2 aA  = f2{bgA, 0.f}, aB  = f2{bgB, 0.f};
                f2 aA2 = f2{0.f, 0.f}, aB2 = f2{0.f, 0.f};
                pk(aA, xwA0, xa); pk(aA2, xwA1, xb);
                pk(aB, xwB0, xa); pk(aB2, xwB1, xb);
                #pragma unroll
                for (int r = 0; r < 16; r += 2) {
                    f2 h0v = hp[r], h1v = hp[r + 1];
                    pk(aA, whA[r], h0v); pk(aA2, whA[r + 1], h1v);
                    pk(aB, whB[r], h0v); pk(aB2, whB[r + 1], h1v);
                }
                f2 sA = aA + aA2, sB = aB + aB2;
                float pA = sA.x + sA.y, pB = sB.x + sB.y;
                float vkeep = kh ? pB : pA;
                float vsend = kh ? pA : pB;
                float full  = vkeep + partner32(vsend, kh);
                float act = gact(full, is_t);
                float x1 = qperm<QP_X1>(act);
                float x2 = qperm<QP_X2>(act);
                float x3 = qperm<QP_X3>(act);
                float p02 = act * x2, p13 = x1 * x3;
                float ig = a1b ? p13 : p02;
                float t1 = a2b ? x2 : act, t2 = a2b ? x3 : x1;
                float fv = a1b ? t1 : t2;
                float o1 = a2b ? act : x2, o2 = a2b ? x1 : x3;
                float ov = a1b ? o1 : o2;
                c0 = fmaf(fv, c0, ig);
                float hn = ov * tanh_s(c0);
                if (pubL) h0s[p][jown] = hn;
                const int tn = (tick + 1) & (TT - 1);
                xa = *((const f2*)&xT[tn][4 * kh]);
                xb = *((const f2*)&xT[tn][4 * kh + 2]);
            }
            __syncthreads();
        }
    } else {
        // ====== LAYER-1 GROUP: computes h1(tick-1) at tick (one behind) ======
        f2 wiA[16], whA[16], wiB[16], whB[16];
        {
            const f2* p0 = (const f2*)(Wih1 + gA * HH + 32 * kh);
            const f2* p1 = (const f2*)(Whh1 + gA * HH + 32 * kh);
            const f2* p2 = (const f2*)(Wih1 + gB * HH + 32 * kh);
            const f2* p3 = (const f2*)(Whh1 + gB * HH + 32 * kh);
            #pragma unroll
            for (int r = 0; r < 16; ++r) {
                wiA[r] = p0[r] * sc; whA[r] = p1[r] * sc;
                wiB[r] = p2[r] * sc; whB[r] = p3[r] * sc;
            }
        }
        const float bgA = (kh == 0) ? (bih1[gA] + bhh1[gA]) * sc : 0.0f;
        const float bgB = (kh == 0) ? (bih1[gB] + bhh1[gB]) * sc : 0.0f;

        float c1 = 0.0f;                 // cell of unit jown

        for (int tick = 0; tick <= TT; ++tick) {
            const int p = tick & 1;
            if (tick > 0) {
                const f2* hp0 = (const f2*)&h0s[p ^ 1][32 * kh];  // h0(tick-1)
                const f2* hp1 = (const f2*)&h1s[p ^ 1][32 * kh];  // h1(tick-2)
                f2 aA  = f2{bgA, 0.f}, aB  = f2{bgB, 0.f};
                f2 aA2 = f2{0.f, 0.f}, aB2 = f2{0.f, 0.f};
                #pragma unroll
                for (int r = 0; r < 16; ++r) {
                    f2 h0v = hp0[r];
                    f2 h1v = hp1[r];
                    pk(aA,  wiA[r], h0v); pk(aA2, whA[r], h1v);
                    pk(aB,  wiB[r], h0v); pk(aB2, whB[r], h1v);
                }
                f2 sA = aA + aA2, sB = aB + aB2;
                float pA = sA.x + sA.y, pB = sB.x + sB.y;
                float vkeep = kh ? pB : pA;
                float vsend = kh ? pA : pB;
                float full  = vkeep + partner32(vsend, kh);
                float act = gact(full, is_t);
                float x1 = qperm<QP_X1>(act);
                float x2 = qperm<QP_X2>(act);
                float x3 = qperm<QP_X3>(act);
                float p02 = act * x2, p13 = x1 * x3;
                float ig = a1b ? p13 : p02;
                float t1 = a2b ? x2 : act, t2 = a2b ? x3 : x1;
                float fv = a1b ? t1 : t2;
                float o1 = a2b ? act : x2, o2 = a2b ? x1 : x3;
                float ov = a1b ? o1 : o2;
                c1 = fmaf(fv, c1, ig);
                float hn = ov * tanh_s(c1);
                if (pubL) h1s[p][jown] = hn;
            }
            __syncthreads();
        }
    }

    // h1(TT-1) was stored at tick TT into h1s[TT&1] = h1s[0]
    if (tid < 10) {
        float y = b1v[tid];
        #pragma unroll
        for (int k = 0; k < HH; ++k) y += W1[tid * HH + k] * h1s[0][k];
        y = (y - rm[tid]) * rsqrtf(rv[tid] + 1e-5f) * gmma[tid] + beta[tid];
        y = fmaxf(y, 0.0f);
        yv[tid] = y * W2[tid];
    }
    __syncthreads();
    if (tid == 0) {
        float sacc = b2[0];
        #pragma unroll
        for (int k = 0; k < 10; ++k) sacc += yv[k];
        out[b] = sacc;
    }
}

extern "C" void kernel_launch(void* const* d_in, const int* in_sizes, int n_in,
                              void* d_out, int out_size, void* d_ws, size_t ws_size,
                              hipStream_t stream) {
    const float* x    = (const float*)d_in[0];
    const float* Wih0 = (const float*)d_in[1];
    const float* Whh0 = (const float*)d_in[2];
    const float* bih0 = (const float*)d_in[3];
    const float* bhh0 = (const float*)d_in[4];
    const float* Wih1 = (const float*)d_in[5];
    const float* Whh1 = (const float*)d_in[6];
    const float* bih1 = (const float*)d_in[7];
    const float* bhh1 = (const float*)d_in[8];
    const float* W1   = (const float*)d_in[9];
    const float* b1   = (const float*)d_in[10];
    const float* gmma = (const float*)d_in[11];
    const float* beta = (const float*)d_in[12];
    const float* rm   = (const float*)d_in[13];
    const float* rv   = (const float*)d_in[14];
    const float* W2   = (const float*)d_in[15];
    const float* b2   = (const float*)d_in[16];

    const int B = in_sizes[0] / (IND * TT);   // 256

    lstm2_fused<<<dim3(B), dim3(NT), 0, stream>>>(
        x, Wih0, Whh0, bih0, bhh0, Wih1, Whh1, bih1, bhh1,
        W1, b1, gmma, beta, rm, rv, W2, b2, (float*)d_out);
}

// Round 10
// 1065.037 us; speedup vs baseline: 1.6416x; 1.3208x over previous
//
#include <hip/hip_runtime.h>
#include <math.h>

#define HH  64
#define TT  2048
#define IND 7
#define NT  512

typedef _Float16 half_t;
typedef _Float16 h2v __attribute__((ext_vector_type(2)));
typedef unsigned int u2v __attribute__((ext_vector_type(2)));

// f16 dot2 with fp32 accumulate: c += a.x*b.x + a.y*b.y  (one VALU instr)
__device__ __forceinline__ float fdot2(h2v a, h2v b, float c) {
#if __has_builtin(__builtin_amdgcn_fdot2)
    return __builtin_amdgcn_fdot2(a, b, c, false);
#else
    return fmaf((float)a.x, (float)b.x, fmaf((float)a.y, (float)b.y, c));
#endif
}

// value held by the lane^32 partner (VALU pipe, v_permlane32_swap)
__device__ __forceinline__ float partner32(float x, int kh) {
#if __has_builtin(__builtin_amdgcn_permlane32_swap)
    u2v r = __builtin_amdgcn_permlane32_swap(__float_as_uint(x), __float_as_uint(x), false, false);
    return kh ? __uint_as_float(r.x) : __uint_as_float(r.y);
#else
    return __shfl_xor(x, 32);
#endif
}

template <int CTRL>
__device__ __forceinline__ float qperm(float x) {
    return __int_as_float(__builtin_amdgcn_update_dpp(0, __float_as_int(x), CTRL, 0xf, 0xf, true));
}
#define QP_X1 0xB1  // quad_perm(1,0,3,2)
#define QP_X2 0x4E  // quad_perm(2,3,0,1)
#define QP_X3 0x1B  // quad_perm(3,2,1,0)

__device__ __forceinline__ float gact(float a, bool is_t) {
    float e  = __expf(-a);
    float sg = __fdividef(1.0f, 1.0f + e);
    return is_t ? fmaf(2.0f, sg, -1.0f) : sg;
}
__device__ __forceinline__ float tanh_s(float c) {
    float e = __expf(-2.0f * c);
    return fmaf(2.0f, __fdividef(1.0f, 1.0f + e), -1.0f);
}

__global__ __launch_bounds__(NT) __attribute__((amdgpu_waves_per_eu(2, 2)))
void lstm2_fused(
    const float* __restrict__ x,     // (B,7,2048)
    const float* __restrict__ Wih0,  // (256,7)
    const float* __restrict__ Whh0,  // (256,64)
    const float* __restrict__ bih0, const float* __restrict__ bhh0,
    const float* __restrict__ Wih1,  // (256,64)
    const float* __restrict__ Whh1,  // (256,64)
    const float* __restrict__ bih1, const float* __restrict__ bhh1,
    const float* __restrict__ W1,    // (10,64)
    const float* __restrict__ b1v,   // (10)
    const float* __restrict__ gmma, const float* __restrict__ beta,
    const float* __restrict__ rm,   const float* __restrict__ rv,
    const float* __restrict__ W2,   // (1,10)
    const float* __restrict__ b2,   // (1)
    float* __restrict__ out)         // (B,1)
{
    const int b    = blockIdx.x;
    const int tid  = threadIdx.x;
    const int grp  = tid >> 8;           // 0: L0 waves 0-3, 1: L1 waves 4-7
    const int lane = tid & 63;
    const int wv   = (tid >> 6) & 3;     // wave in group
    const int s    = lane & 3;           // gate 0:i 1:f 2:g 3:o (quad-local)
    const int q    = (lane >> 2) & 7;
    const int kh   = lane >> 5;          // k-half (lane bit 5)
    const int jA   = (wv << 3) | q;      // unit A: 0..31
    const int gA   = (s << 6) | jA;      // gate row of unit A
    const int gB   = gA + 32;            // gate row of unit B (jA+32)
    const int jown = jA + (kh << 5);     // unit this lane finishes

    __shared__ __align__(16) half_t xTh[TT][8];   // 32 KB, f16 x, [7]=0 pad
    __shared__ __align__(16) half_t h0s[2][HH];   // f16 hidden, double-buffered
    __shared__ __align__(16) half_t h1s[2][HH];
    __shared__ float yv[10];

    // ---- stage x[b] transposed, converted to f16 ----
    {
        const float* xg = x + (size_t)b * (IND * TT);
        for (int i = tid; i < IND * TT; i += NT) {
            int d = i >> 11;
            int t = i & (TT - 1);
            xTh[t][d] = (half_t)xg[i];
        }
        for (int t = tid; t < TT; t += NT) xTh[t][7] = (half_t)0.0f;
        if (tid < HH) {
            h0s[1][tid] = (half_t)0.0f;
            h1s[0][tid] = (half_t)0.0f;
            h1s[1][tid] = (half_t)0.0f;
        }
    }

    const float sc   = (s == 2) ? 2.0f : 1.0f;   // exact pre-scale for tanh gate
    const bool  is_t = (s == 2);
    const bool  a1b  = (s & 1) != 0;
    const bool  a2b  = (s & 2) != 0;
    const bool  pubL = (s == 0);                 // one publisher per unit

    __syncthreads();

    if (grp == 0) {
        // ============ LAYER-0 GROUP: computes h0(tick) at tick ============
        h2v whA[16], whB[16];
        {
            const float* pA = Whh0 + gA * HH + 32 * kh;
            const float* pB = Whh0 + gB * HH + 32 * kh;
            #pragma unroll
            for (int r = 0; r < 16; ++r) {
                whA[r] = h2v{(half_t)(pA[2*r] * sc), (half_t)(pA[2*r+1] * sc)};
                whB[r] = h2v{(half_t)(pB[2*r] * sc), (half_t)(pB[2*r+1] * sc)};
            }
        }
        h2v xwA0, xwA1, xwB0, xwB1;
        if (kh == 0) {
            xwA0 = h2v{(half_t)(Wih0[gA*IND+0]*sc), (half_t)(Wih0[gA*IND+1]*sc)};
            xwA1 = h2v{(half_t)(Wih0[gA*IND+2]*sc), (half_t)(Wih0[gA*IND+3]*sc)};
            xwB0 = h2v{(half_t)(Wih0[gB*IND+0]*sc), (half_t)(Wih0[gB*IND+1]*sc)};
            xwB1 = h2v{(half_t)(Wih0[gB*IND+2]*sc), (half_t)(Wih0[gB*IND+3]*sc)};
        } else {
            xwA0 = h2v{(half_t)(Wih0[gA*IND+4]*sc), (half_t)(Wih0[gA*IND+5]*sc)};
            xwA1 = h2v{(half_t)(Wih0[gA*IND+6]*sc), (half_t)0.0f};
            xwB0 = h2v{(half_t)(Wih0[gB*IND+4]*sc), (half_t)(Wih0[gB*IND+5]*sc)};
            xwB1 = h2v{(half_t)(Wih0[gB*IND+6]*sc), (half_t)0.0f};
        }
        const float bgA = (kh == 0) ? (bih0[gA] + bhh0[gA]) * sc : 0.0f;
        const float bgB = (kh == 0) ? (bih0[gB] + bhh0[gB]) * sc : 0.0f;

        float c0 = 0.0f;                 // cell of unit jown
        h2v xa = ((const h2v*)&xTh[0][4 * kh])[0];
        h2v xb = ((const h2v*)&xTh[0][4 * kh])[1];

        for (int tick = 0; tick <= TT; ++tick) {
            const int p = tick & 1;
            if (tick < TT) {
                const h2v* hp = (const h2v*)&h0s[p ^ 1][32 * kh];
                float aA0 = bgA, aA1 = 0.0f, aB0 = bgB, aB1 = 0.0f;
                aA0 = fdot2(xwA0, xa, aA0); aA1 = fdot2(xwA1, xb, aA1);
                aB0 = fdot2(xwB0, xa, aB0); aB1 = fdot2(xwB1, xb, aB1);
                #pragma unroll
                for (int r = 0; r < 16; r += 2) {
                    h2v h0v = hp[r], h1v = hp[r + 1];
                    aA0 = fdot2(whA[r], h0v, aA0); aA1 = fdot2(whA[r + 1], h1v, aA1);
                    aB0 = fdot2(whB[r], h0v, aB0); aB1 = fdot2(whB[r + 1], h1v, aB1);
                }
                float pA = aA0 + aA1, pB = aB0 + aB1;
                float vkeep = kh ? pB : pA;
                float vsend = kh ? pA : pB;
                float full  = vkeep + partner32(vsend, kh);
                float act = gact(full, is_t);
                float x1 = qperm<QP_X1>(act);
                float x2 = qperm<QP_X2>(act);
                float x3 = qperm<QP_X3>(act);
                float p02 = act * x2, p13 = x1 * x3;
                float ig = a1b ? p13 : p02;
                float t1 = a2b ? x2 : act, t2 = a2b ? x3 : x1;
                float fv = a1b ? t1 : t2;
                float o1 = a2b ? act : x2, o2 = a2b ? x1 : x3;
                float ov = a1b ? o1 : o2;
                c0 = fmaf(fv, c0, ig);
                float hn = ov * tanh_s(c0);
                if (pubL) h0s[p][jown] = (half_t)hn;
                const int tn = (tick + 1) & (TT - 1);
                xa = ((const h2v*)&xTh[tn][4 * kh])[0];
                xb = ((const h2v*)&xTh[tn][4 * kh])[1];
            }
            __syncthreads();
        }
    } else {
        // ====== LAYER-1 GROUP: computes h1(tick-1) at tick (one behind) ======
        h2v wiA[16], whA[16], wiB[16], whB[16];
        {
            const float* p0 = Wih1 + gA * HH + 32 * kh;
            const float* p1 = Whh1 + gA * HH + 32 * kh;
            const float* p2 = Wih1 + gB * HH + 32 * kh;
            const float* p3 = Whh1 + gB * HH + 32 * kh;
            #pragma unroll
            for (int r = 0; r < 16; ++r) {
                wiA[r] = h2v{(half_t)(p0[2*r] * sc), (half_t)(p0[2*r+1] * sc)};
                whA[r] = h2v{(half_t)(p1[2*r] * sc), (half_t)(p1[2*r+1] * sc)};
                wiB[r] = h2v{(half_t)(p2[2*r] * sc), (half_t)(p2[2*r+1] * sc)};
                whB[r] = h2v{(half_t)(p3[2*r] * sc), (half_t)(p3[2*r+1] * sc)};
            }
        }
        const float bgA = (kh == 0) ? (bih1[gA] + bhh1[gA]) * sc : 0.0f;
        const float bgB = (kh == 0) ? (bih1[gB] + bhh1[gB]) * sc : 0.0f;

        float c1 = 0.0f;                 // cell of unit jown

        for (int tick = 0; tick <= TT; ++tick) {
            const int p = tick & 1;
            if (tick > 0) {
                const h2v* hp0 = (const h2v*)&h0s[p ^ 1][32 * kh];  // h0(tick-1)
                const h2v* hp1 = (const h2v*)&h1s[p ^ 1][32 * kh];  // h1(tick-2)
                float aA0 = bgA, aA1 = 0.0f, aB0 = bgB, aB1 = 0.0f;
                #pragma unroll
                for (int r = 0; r < 16; ++r) {
                    h2v h0v = hp0[r];
                    h2v h1v = hp1[r];
                    aA0 = fdot2(wiA[r], h0v, aA0); aA1 = fdot2(whA[r], h1v, aA1);
                    aB0 = fdot2(wiB[r], h0v, aB0); aB1 = fdot2(whB[r], h1v, aB1);
                }
                float pA = aA0 + aA1, pB = aB0 + aB1;
                float vkeep = kh ? pB : pA;
                float vsend = kh ? pA : pB;
                float full  = vkeep + partner32(vsend, kh);
                float act = gact(full, is_t);
                float x1 = qperm<QP_X1>(act);
                float x2 = qperm<QP_X2>(act);
                float x3 = qperm<QP_X3>(act);
                float p02 = act * x2, p13 = x1 * x3;
                float ig = a1b ? p13 : p02;
                float t1 = a2b ? x2 : act, t2 = a2b ? x3 : x1;
                float fv = a1b ? t1 : t2;
                float o1 = a2b ? act : x2, o2 = a2b ? x1 : x3;
                float ov = a1b ? o1 : o2;
                c1 = fmaf(fv, c1, ig);
                float hn = ov * tanh_s(c1);
                if (pubL) h1s[p][jown] = (half_t)hn;
            }
            __syncthreads();
        }
    }

    // h1(TT-1) was stored at tick TT into h1s[TT&1] = h1s[0]
    if (tid < 10) {
        float y = b1v[tid];
        #pragma unroll
        for (int k = 0; k < HH; ++k) y += W1[tid * HH + k] * (float)h1s[0][k];
        y = (y - rm[tid]) * rsqrtf(rv[tid] + 1e-5f) * gmma[tid] + beta[tid];
        y = fmaxf(y, 0.0f);
        yv[tid] = y * W2[tid];
    }
    __syncthreads();
    if (tid == 0) {
        float sacc = b2[0];
        #pragma unroll
        for (int k = 0; k < 10; ++k) sacc += yv[k];
        out[b] = sacc;
    }
}

extern "C" void kernel_launch(void* const* d_in, const int* in_sizes, int n_in,
                              void* d_out, int out_size, void* d_ws, size_t ws_size,
                              hipStream_t stream) {
    const float* x    = (const float*)d_in[0];
    const float* Wih0 = (const float*)d_in[1];
    const float* Whh0 = (const float*)d_in[2];
    const float* bih0 = (const float*)d_in[3];
    const float* bhh0 = (const float*)d_in[4];
    const float* Wih1 = (const float*)d_in[5];
    const float* Whh1 = (const float*)d_in[6];
    const float* bih1 = (const float*)d_in[7];
    const float* bhh1 = (const float*)d_in[8];
    const float* W1   = (const float*)d_in[9];
    const float* b1   = (const float*)d_in[10];
    const float* gmma = (const float*)d_in[11];
    const float* beta = (const float*)d_in[12];
    const float* rm   = (const float*)d_in[13];
    const float* rv   = (const float*)d_in[14];
    const float* W2   = (const float*)d_in[15];
    const float* b2   = (const float*)d_in[16];

    const int B = in_sizes[0] / (IND * TT);   // 256

    lstm2_fused<<<dim3(B), dim3(NT), 0, stream>>>(
        x, Wih0, Whh0, bih0, bhh0, Wih1, Whh1, bih1, bhh1,
        W1, b1, gmma, beta, rm, rv, W2, b2, (float*)d_out);
}

// Round 12
// 1061.258 us; speedup vs baseline: 1.6474x; 1.0036x over previous
//
#include <hip/hip_runtime.h>
#include <math.h>

#define HH  64
#define TT  2048
#define IND 7
#define NT  512

typedef _Float16 half_t;
typedef _Float16 h2v __attribute__((ext_vector_type(2)));
typedef _Float16 h4v __attribute__((ext_vector_type(4)));
typedef _Float16 h8v __attribute__((ext_vector_type(8)));
typedef unsigned int u2v __attribute__((ext_vector_type(2)));

// constant-index h2v slice of an h8v: exact VGPR subregister, no repack
#define S2C(V, I) __builtin_shufflevector(V, V, 2*(I), 2*(I)+1)
#define S2L(V)    __builtin_shufflevector(V, V, 0, 1)
#define S2H(V)    __builtin_shufflevector(V, V, 2, 3)

// f16 dot2 with fp32 accumulate: c += a.x*b.x + a.y*b.y  (one VALU instr)
__device__ __forceinline__ float fdot2(h2v a, h2v b, float c) {
#if __has_builtin(__builtin_amdgcn_fdot2)
    return __builtin_amdgcn_fdot2(a, b, c, false);
#else
    return fmaf((float)a.x, (float)b.x, fmaf((float)a.y, (float)b.y, c));
#endif
}

// value held by the lane^32 partner (VALU pipe, v_permlane32_swap)
__device__ __forceinline__ float partner32(float x, int kh) {
#if __has_builtin(__builtin_amdgcn_permlane32_swap)
    u2v r = __builtin_amdgcn_permlane32_swap(__float_as_uint(x), __float_as_uint(x), false, false);
    return kh ? __uint_as_float(r.x) : __uint_as_float(r.y);
#else
    return __shfl_xor(x, 32);
#endif
}

template <int CTRL>
__device__ __forceinline__ float qperm(float x) {
    return __int_as_float(__builtin_amdgcn_update_dpp(0, __float_as_int(x), CTRL, 0xf, 0xf, true));
}
#define QP_X1 0xB1  // quad_perm(1,0,3,2)
#define QP_X2 0x4E  // quad_perm(2,3,0,1)
#define QP_X3 0x1B  // quad_perm(3,2,1,0)

__device__ __forceinline__ float gact(float a, bool is_t) {
    float e  = __expf(-a);
    float sg = __fdividef(1.0f, 1.0f + e);
    return is_t ? fmaf(2.0f, sg, -1.0f) : sg;
}
__device__ __forceinline__ float tanh_s(float c) {
    float e = __expf(-2.0f * c);
    return fmaf(2.0f, __fdividef(1.0f, 1.0f + e), -1.0f);
}

__global__ __launch_bounds__(NT) __attribute__((amdgpu_waves_per_eu(2, 2)))
void lstm2_fused(
    const float* __restrict__ x,     // (B,7,2048)
    const float* __restrict__ Wih0,  // (256,7)
    const float* __restrict__ Whh0,  // (256,64)
    const float* __restrict__ bih0, const float* __restrict__ bhh0,
    const float* __restrict__ Wih1,  // (256,64)
    const float* __restrict__ Whh1,  // (256,64)
    const float* __restrict__ bih1, const float* __restrict__ bhh1,
    const float* __restrict__ W1,    // (10,64)
    const float* __restrict__ b1v,   // (10)
    const float* __restrict__ gmma, const float* __restrict__ beta,
    const float* __restrict__ rm,   const float* __restrict__ rv,
    const float* __restrict__ W2,   // (1,10)
    const float* __restrict__ b2,   // (1)
    float* __restrict__ out)         // (B,1)
{
    const int b    = blockIdx.x;
    const int tid  = threadIdx.x;
    const int grp  = tid >> 8;           // 0: L0 waves 0-3, 1: L1 waves 4-7
    const int lane = tid & 63;
    const int wv   = (tid >> 6) & 3;     // wave in group
    const int s    = lane & 3;           // gate 0:i 1:f 2:g 3:o (quad-local)
    const int q    = (lane >> 2) & 7;
    const int kh   = lane >> 5;          // k-half (lane bit 5)
    const int jA   = (wv << 3) | q;      // unit A: 0..31
    const int gA   = (s << 6) | jA;      // gate row of unit A
    const int gB   = gA + 32;            // gate row of unit B (jA+32)
    const int jown = jA + (kh << 5);     // unit this lane finishes

    __shared__ __align__(16) half_t xTh[TT][8];   // 32 KB, f16 x, [7]=0 pad
    __shared__ __align__(16) half_t h0s[2][HH];   // f16 hidden, double-buffered
    __shared__ __align__(16) half_t h1s[2][HH];
    __shared__ float yv[10];

    // ---- stage x[b] transposed, converted to f16 ----
    {
        const float* xg = x + (size_t)b * (IND * TT);
        for (int i = tid; i < IND * TT; i += NT) {
            int d = i >> 11;
            int t = i & (TT - 1);
            xTh[t][d] = (half_t)xg[i];
        }
        for (int t = tid; t < TT; t += NT) xTh[t][7] = (half_t)0.0f;
        if (tid < HH) {
            h0s[1][tid] = (half_t)0.0f;
            h1s[0][tid] = (half_t)0.0f;
            h1s[1][tid] = (half_t)0.0f;
        }
    }

    const float sc   = (s == 2) ? 2.0f : 1.0f;   // exact pre-scale for tanh gate
    const bool  is_t = (s == 2);
    const bool  a1b  = (s & 1) != 0;
    const bool  a2b  = (s & 2) != 0;
    const bool  pubL = (s == 0);                 // one publisher per unit

    __syncthreads();

    if (grp == 0) {
        // ============ LAYER-0 GROUP: computes h0(tick) at tick ============
        h2v whA[16], whB[16];
        {
            const float* pA = Whh0 + gA * HH + 32 * kh;
            const float* pB = Whh0 + gB * HH + 32 * kh;
            #pragma unroll
            for (int r = 0; r < 16; ++r) {
                whA[r] = h2v{(half_t)(pA[2*r] * sc), (half_t)(pA[2*r+1] * sc)};
                whB[r] = h2v{(half_t)(pB[2*r] * sc), (half_t)(pB[2*r+1] * sc)};
            }
        }
        h2v xwA0, xwA1, xwB0, xwB1;
        if (kh == 0) {
            xwA0 = h2v{(half_t)(Wih0[gA*IND+0]*sc), (half_t)(Wih0[gA*IND+1]*sc)};
            xwA1 = h2v{(half_t)(Wih0[gA*IND+2]*sc), (half_t)(Wih0[gA*IND+3]*sc)};
            xwB0 = h2v{(half_t)(Wih0[gB*IND+0]*sc), (half_t)(Wih0[gB*IND+1]*sc)};
            xwB1 = h2v{(half_t)(Wih0[gB*IND+2]*sc), (half_t)(Wih0[gB*IND+3]*sc)};
        } else {
            xwA0 = h2v{(half_t)(Wih0[gA*IND+4]*sc), (half_t)(Wih0[gA*IND+5]*sc)};
            xwA1 = h2v{(half_t)(Wih0[gA*IND+6]*sc), (half_t)0.0f};
            xwB0 = h2v{(half_t)(Wih0[gB*IND+4]*sc), (half_t)(Wih0[gB*IND+5]*sc)};
            xwB1 = h2v{(half_t)(Wih0[gB*IND+6]*sc), (half_t)0.0f};
        }
        const float bgA = (kh == 0) ? (bih0[gA] + bhh0[gA]) * sc : 0.0f;
        const float bgB = (kh == 0) ? (bih0[gB] + bhh0[gB]) * sc : 0.0f;

        float c0 = 0.0f;                 // cell of unit jown
        h4v xv = *((const h4v*)&xTh[0][4 * kh]);   // one b64 read

        for (int tick = 0; tick <= TT; ++tick) {
            const int p = tick & 1;
            if (tick < TT) {
                const h8v* hp = (const h8v*)&h0s[p ^ 1][32 * kh];  // 4 x b128
                h8v H0 = hp[0], H1 = hp[1], H2 = hp[2], H3 = hp[3];
                float aA0 = bgA, aA1 = 0.0f, aB0 = bgB, aB1 = 0.0f;
                aA0 = fdot2(xwA0, S2L(xv), aA0); aA1 = fdot2(xwA1, S2H(xv), aA1);
                aB0 = fdot2(xwB0, S2L(xv), aB0); aB1 = fdot2(xwB1, S2H(xv), aB1);
#define L0_STEP(I) \
                aA0 = fdot2(whA[I],      S2C(H0, I), aA0); \
                aA1 = fdot2(whA[4 + I],  S2C(H1, I), aA1); \
                aB0 = fdot2(whB[I],      S2C(H0, I), aB0); \
                aB1 = fdot2(whB[4 + I],  S2C(H1, I), aB1); \
                aA0 = fdot2(whA[8 + I],  S2C(H2, I), aA0); \
                aA1 = fdot2(whA[12 + I], S2C(H3, I), aA1); \
                aB0 = fdot2(whB[8 + I],  S2C(H2, I), aB0); \
                aB1 = fdot2(whB[12 + I], S2C(H3, I), aB1);
                L0_STEP(0) L0_STEP(1) L0_STEP(2) L0_STEP(3)
#undef L0_STEP
                float pA = aA0 + aA1, pB = aB0 + aB1;
                float vkeep = kh ? pB : pA;
                float vsend = kh ? pA : pB;
                float full  = vkeep + partner32(vsend, kh);
                float act = gact(full, is_t);
                float x1 = qperm<QP_X1>(act);
                float x2 = qperm<QP_X2>(act);
                float x3 = qperm<QP_X3>(act);
                float p02 = act * x2, p13 = x1 * x3;
                float ig = a1b ? p13 : p02;
                float t1 = a2b ? x2 : act, t2 = a2b ? x3 : x1;
                float fv = a1b ? t1 : t2;
                float o1 = a2b ? act : x2, o2 = a2b ? x1 : x3;
                float ov = a1b ? o1 : o2;
                c0 = fmaf(fv, c0, ig);
                float hn = ov * tanh_s(c0);
                if (pubL) h0s[p][jown] = (half_t)hn;
                const int tn = (tick + 1) & (TT - 1);
                xv = *((const h4v*)&xTh[tn][4 * kh]);
            }
            __syncthreads();
        }
    } else {
        // ====== LAYER-1 GROUP: computes h1(tick-1) at tick (one behind) ======
        h2v wiA[16], whA[16], wiB[16], whB[16];
        {
            const float* p0 = Wih1 + gA * HH + 32 * kh;
            const float* p1 = Whh1 + gA * HH + 32 * kh;
            const float* p2 = Wih1 + gB * HH + 32 * kh;
            const float* p3 = Whh1 + gB * HH + 32 * kh;
            #pragma unroll
            for (int r = 0; r < 16; ++r) {
                wiA[r] = h2v{(half_t)(p0[2*r] * sc), (half_t)(p0[2*r+1] * sc)};
                whA[r] = h2v{(half_t)(p1[2*r] * sc), (half_t)(p1[2*r+1] * sc)};
                wiB[r] = h2v{(half_t)(p2[2*r] * sc), (half_t)(p2[2*r+1] * sc)};
                whB[r] = h2v{(half_t)(p3[2*r] * sc), (half_t)(p3[2*r+1] * sc)};
            }
        }
        const float bgA = (kh == 0) ? (bih1[gA] + bhh1[gA]) * sc : 0.0f;
        const float bgB = (kh == 0) ? (bih1[gB] + bhh1[gB]) * sc : 0.0f;

        float c1 = 0.0f;                 // cell of unit jown

        for (int tick = 0; tick <= TT; ++tick) {
            const int p = tick & 1;
            if (tick > 0) {
                const h8v* hp0 = (const h8v*)&h0s[p ^ 1][32 * kh];  // h0(tick-1)
                const h8v* hp1 = (const h8v*)&h1s[p ^ 1][32 * kh];  // h1(tick-2)
                h8v F0 = hp0[0], F1 = hp0[1], F2 = hp0[2], F3 = hp0[3];
                h8v G0 = hp1[0], G1 = hp1[1], G2 = hp1[2], G3 = hp1[3];
                float aA0 = bgA, aA1 = 0.0f, aB0 = bgB, aB1 = 0.0f;
#define L1_STEP(I) \
                aA0 = fdot2(wiA[I],      S2C(F0, I), aA0); \
                aA1 = fdot2(whA[I],      S2C(G0, I), aA1); \
                aB0 = fdot2(wiB[I],      S2C(F0, I), aB0); \
                aB1 = fdot2(whB[I],      S2C(G0, I), aB1); \
                aA0 = fdot2(wiA[4 + I],  S2C(F1, I), aA0); \
                aA1 = fdot2(whA[4 + I],  S2C(G1, I), aA1); \
                aB0 = fdot2(wiB[4 + I],  S2C(F1, I), aB0); \
                aB1 = fdot2(whB[4 + I],  S2C(G1, I), aB1); \
                aA0 = fdot2(wiA[8 + I],  S2C(F2, I), aA0); \
                aA1 = fdot2(whA[8 + I],  S2C(G2, I), aA1); \
                aB0 = fdot2(wiB[8 + I],  S2C(F2, I), aB0); \
                aB1 = fdot2(whB[8 + I],  S2C(G2, I), aB1); \
                aA0 = fdot2(wiA[12 + I], S2C(F3, I), aA0); \
                aA1 = fdot2(whA[12 + I], S2C(G3, I), aA1); \
                aB0 = fdot2(wiB[12 + I], S2C(F3, I), aB0); \
                aB1 = fdot2(whB[12 + I], S2C(G3, I), aB1);
                L1_STEP(0) L1_STEP(1) L1_STEP(2) L1_STEP(3)
#undef L1_STEP
                float pA = aA0 + aA1, pB = aB0 + aB1;
                float vkeep = kh ? pB : pA;
                float vsend = kh ? pA : pB;
                float full  = vkeep + partner32(vsend, kh);
                float act = gact(full, is_t);
                float x1 = qperm<QP_X1>(act);
                float x2 = qperm<QP_X2>(act);
                float x3 = qperm<QP_X3>(act);
                float p02 = act * x2, p13 = x1 * x3;
                float ig = a1b ? p13 : p02;
                float t1 = a2b ? x2 : act, t2 = a2b ? x3 : x1;
                float fv = a1b ? t1 : t2;
                float o1 = a2b ? act : x2, o2 = a2b ? x1 : x3;
                float ov = a1b ? o1 : o2;
                c1 = fmaf(fv, c1, ig);
                float hn = ov * tanh_s(c1);
                if (pubL) h1s[p][jown] = (half_t)hn;
            }
            __syncthreads();
        }
    }

    // h1(TT-1) was stored at tick TT into h1s[TT&1] = h1s[0]
    if (tid < 10) {
        float y = b1v[tid];
        #pragma unroll
        for (int k = 0; k < HH; ++k) y += W1[tid * HH + k] * (float)h1s[0][k];
        y = (y - rm[tid]) * rsqrtf(rv[tid] + 1e-5f) * gmma[tid] + beta[tid];
        y = fmaxf(y, 0.0f);
        yv[tid] = y * W2[tid];
    }
    __syncthreads();
    if (tid == 0) {
        float sacc = b2[0];
        #pragma unroll
        for (int k = 0; k < 10; ++k) sacc += yv[k];
        out[b] = sacc;
    }
}

extern "C" void kernel_launch(void* const* d_in, const int* in_sizes, int n_in,
                              void* d_out, int out_size, void* d_ws, size_t ws_size,
                              hipStream_t stream) {
    const float* x    = (const float*)d_in[0];
    const float* Wih0 = (const float*)d_in[1];
    const float* Whh0 = (const float*)d_in[2];
    const float* bih0 = (const float*)d_in[3];
    const float* bhh0 = (const float*)d_in[4];
    const float* Wih1 = (const float*)d_in[5];
    const float* Whh1 = (const float*)d_in[6];
    const float* bih1 = (const float*)d_in[7];
    const float* bhh1 = (const float*)d_in[8];
    const float* W1   = (const float*)d_in[9];
    const float* b1   = (const float*)d_in[10];
    const float* gmma = (const float*)d_in[11];
    const float* beta = (const float*)d_in[12];
    const float* rm   = (const float*)d_in[13];
    const float* rv   = (const float*)d_in[14];
    const float* W2   = (const float*)d_in[15];
    const float* b2   = (const float*)d_in[16];

    const int B = in_sizes[0] / (IND * TT);   // 256

    lstm2_fused<<<dim3(B), dim3(NT), 0, stream>>>(
        x, Wih0, Whh0, bih0, bhh0, Wih1, Whh1, bih1, bhh1,
        W1, b1, gmma, beta, rm, rv, W2, b2, (float*)d_out);
}